// Round 3
// baseline (19136.754 us; speedup 1.0000x reference)
//
#include <hip/hip_runtime.h>

// Problem constants (B,S,F,L) = (512, 1024, 64, 128)
constexpr int Bn = 512;
constexpr int Sn = 1024;
constexpr int Fn = 64;
constexpr int Ln = 128;
constexpr int Gn = 4 * Ln;  // 512 gate rows (i,f,g,o)

// ---- cross-lane helpers ----
template <int CTRL>
__device__ __forceinline__ float dpp_add(float v) {
  int s = __builtin_amdgcn_mov_dpp(__float_as_int(v), CTRL, 0xF, 0xF, true);
  return v + __int_as_float(s);
}
// 0xB1 = quad_perm(1,0,3,2) = xor1; 0x4E = quad_perm(2,3,0,1) = xor2
__device__ __forceinline__ float swz4_add(float v) {  // xor4 via ds_swizzle bitmode
  int s = __builtin_amdgcn_ds_swizzle(__float_as_int(v), 0x101F);
  return v + __int_as_float(s);
}

__device__ __forceinline__ float fsig(float v) {
  return __builtin_amdgcn_rcpf(1.0f + __expf(-v));
}
__device__ __forceinline__ float ftanh(float v) {
  return 2.0f * __builtin_amdgcn_rcpf(1.0f + __expf(-2.0f * v)) - 1.0f;
}

// Fold decoder dense layer into the decoder recurrence:
//   W_comb[t,l] = W_hh_dec[t,l] + sum_j W_ih_dec[t,j] * W_dense[j,l]
//   b_comb[t]   = b_ih_dec[t] + b_hh_dec[t] + sum_j W_ih_dec[t,j] * b_dense[j]
__global__ void combine_dec_kernel(const float* __restrict__ Wih, const float* __restrict__ Whh,
                                   const float* __restrict__ bih, const float* __restrict__ bhh,
                                   const float* __restrict__ Wd, const float* __restrict__ bd,
                                   float* __restrict__ Wc, float* __restrict__ bc) {
  const int t = blockIdx.x;   // gate row 0..511
  const int l = threadIdx.x;  // latent col 0..127
  float s = Whh[t * Ln + l];
#pragma unroll
  for (int j = 0; j < Fn; ++j) s += Wih[t * Fn + j] * Wd[j * Ln + l];
  Wc[t * Ln + l] = s;
  if (l == 0) {
    float sb = bih[t] + bhh[t];
#pragma unroll
    for (int j = 0; j < Fn; ++j) sb += Wih[t * Fn + j] * bd[j];
    bc[t] = sb;
  }
}

// Persistent RNN: 256 blocks x 512 threads (8 waves -> 2 waves/SIMD, 256-VGPR
// cap so the 192-float weight set stays in arch VGPRs -- round 2's 1024-thread
// version was capped at 128 and the compiler moved weights to AGPRs, doubling
// VALU with v_accvgpr copies).
// Thread t: q = t&3 (K-quarter), rA = t>>2 (latent). Owns gate rows
// {rA, rA+128, rA+256, rA+384} = (i,f,g,o) of latent rA -> after the 4-lane
// DPP quad reduce, the cell update is LOCAL (no gate LDS round-trip, one
// barrier per step). h and x double-buffered in LDS, quarter regions padded
// (68/36 floats) so the 4 broadcast read addresses stagger across banks.
__global__ __launch_bounds__(512, 2) void rae_persistent_kernel(
    const float* __restrict__ x,
    const float* __restrict__ Wih_e, const float* __restrict__ Whh_e,
    const float* __restrict__ bih_e, const float* __restrict__ bhh_e,
    const float* __restrict__ Wc, const float* __restrict__ bc,
    const float* __restrict__ Wd, const float* __restrict__ bd,
    float* __restrict__ out) {
  const int t = threadIdx.x;
  const int q = t & 3;    // K-quarter: x[16q..16q+16), h[32q..32q+32)
  const int rA = t >> 2;  // latent 0..127
  const int b0 = blockIdx.x * 2;

  __shared__ __align__(16) float hs[2][4][68];  // [buf][quarter][32 latents x 2 elems + 4 pad]
  __shared__ __align__(16) float xs[2][4][36];  // [buf][quarter][16 feats x 2 elems + 4 pad]

  // ---- encoder weights: 4 gate rows x (32 h + 16 x) = 192 fp32 regs ----
  float wh[4][32], wx[4][16], bias[4];
#pragma unroll
  for (int g = 0; g < 4; ++g) {
    const int row = g * Ln + rA;
    const float4* ph = (const float4*)(Whh_e + row * Ln + q * 32);
#pragma unroll
    for (int k = 0; k < 8; ++k) {
      float4 v = ph[k];
      wh[g][4 * k] = v.x; wh[g][4 * k + 1] = v.y; wh[g][4 * k + 2] = v.z; wh[g][4 * k + 3] = v.w;
    }
    const float4* px = (const float4*)(Wih_e + row * Fn + q * 16);
#pragma unroll
    for (int k = 0; k < 4; ++k) {
      float4 v = px[k];
      wx[g][4 * k] = v.x; wx[g][4 * k + 1] = v.y; wx[g][4 * k + 2] = v.z; wx[g][4 * k + 3] = v.w;
    }
    bias[g] = bih_e[row] + bhh_e[row];
  }

  float c = 0.0f;  // valid on lanes q<2: cell state for (latent rA, elem q)

  // x prefetch slot: t<128 -> (elem e_, feature f_)
  const int f_ = t & 63, e_ = (t >> 6) & 1;
  const float* xbase = x + (size_t)(b0 + e_) * Sn * Fn + f_;

  if (t < Ln) {
    hs[0][t >> 5][(t & 31) * 2] = 0.0f;
    hs[0][t >> 5][(t & 31) * 2 + 1] = 0.0f;
    xs[0][f_ >> 4][(f_ & 15) * 2 + e_] = xbase[0];
  }
  __syncthreads();

  // ================= encoder: 1024 steps =================
  for (int step = 0; step < Sn; ++step) {
    const int cur = step & 1, nx = cur ^ 1;
    float xv = 0.0f;
    if (t < Ln && step + 1 < Sn) xv = xbase[(size_t)(step + 1) * Fn];

    float a[4][2];
#pragma unroll
    for (int g = 0; g < 4; ++g) { a[g][0] = 0.0f; a[g][1] = 0.0f; }

    const float4* x4 = (const float4*)&xs[cur][q][0];
#pragma unroll
    for (int k = 0; k < 8; ++k) {  // features 16q+2k, +2k+1, both elems
      float4 v = x4[k];
#pragma unroll
      for (int g = 0; g < 4; ++g) {
        a[g][0] += wx[g][2 * k] * v.x + wx[g][2 * k + 1] * v.z;
        a[g][1] += wx[g][2 * k] * v.y + wx[g][2 * k + 1] * v.w;
      }
    }
    const float4* h4 = (const float4*)&hs[cur][q][0];
#pragma unroll
    for (int k = 0; k < 16; ++k) {  // latents 32q+2k, +2k+1, both elems
      float4 v = h4[k];
#pragma unroll
      for (int g = 0; g < 4; ++g) {
        a[g][0] += wh[g][2 * k] * v.x + wh[g][2 * k + 1] * v.z;
        a[g][1] += wh[g][2 * k] * v.y + wh[g][2 * k + 1] * v.w;
      }
    }
    // quad all-reduce: every lane gets full sums for all 4 gates x 2 elems
#pragma unroll
    for (int g = 0; g < 4; ++g) {
#pragma unroll
      for (int e = 0; e < 2; ++e) {
        a[g][e] = dpp_add<0xB1>(a[g][e]);
        a[g][e] = dpp_add<0x4E>(a[g][e]);
      }
    }
    if (q < 2) {  // lane q handles elem q: local cell update
      float gi = fsig(a[0][q] + bias[0]);
      float gf = fsig(a[1][q] + bias[1]);
      float gg = ftanh(a[2][q] + bias[2]);
      float go = fsig(a[3][q] + bias[3]);
      c = gf * c + gi * gg;
      hs[nx][rA >> 5][(rA & 31) * 2 + q] = go * ftanh(c);
    }
    if (t < Ln && step + 1 < Sn) xs[nx][f_ >> 4][(f_ & 15) * 2 + e_] = xv;
    __syncthreads();
  }

  // ================= decoder: 1024 steps =================
#pragma unroll
  for (int g = 0; g < 4; ++g) {  // reload wh with folded W_comb
    const int row = g * Ln + rA;
    const float4* pc = (const float4*)(Wc + row * Ln + q * 32);
#pragma unroll
    for (int k = 0; k < 8; ++k) {
      float4 v = pc[k];
      wh[g][4 * k] = v.x; wh[g][4 * k + 1] = v.y; wh[g][4 * k + 2] = v.z; wh[g][4 * k + 3] = v.w;
    }
    bias[g] = bc[row];
  }
  // dense epilogue: 8 lanes per output feature, 16 latents each
  const int oj = t >> 3, sl = t & 7;
  float dw[16];
  {
    const float4* pd = (const float4*)(Wd + oj * Ln + sl * 16);
#pragma unroll
    for (int k = 0; k < 4; ++k) {
      float4 v = pd[k];
      dw[4 * k] = v.x; dw[4 * k + 1] = v.y; dw[4 * k + 2] = v.z; dw[4 * k + 3] = v.w;
    }
  }
  const float dbias = bd[oj];
  float* opA = out + (size_t)b0 * Sn * Fn + (size_t)(Sn - 1) * Fn + oj;
  float* opB = opA + (size_t)Sn * Fn;

  for (int step = 0; step < Sn; ++step) {
    const int cur = step & 1, nx = cur ^ 1;
    float a[4][2];
#pragma unroll
    for (int g = 0; g < 4; ++g) { a[g][0] = 0.0f; a[g][1] = 0.0f; }

    const float4* h4 = (const float4*)&hs[cur][q][0];
#pragma unroll
    for (int k = 0; k < 16; ++k) {
      float4 v = h4[k];
#pragma unroll
      for (int g = 0; g < 4; ++g) {
        a[g][0] += wh[g][2 * k] * v.x + wh[g][2 * k + 1] * v.z;
        a[g][1] += wh[g][2 * k] * v.y + wh[g][2 * k + 1] * v.w;
      }
    }
#pragma unroll
    for (int g = 0; g < 4; ++g) {
#pragma unroll
      for (int e = 0; e < 2; ++e) {
        a[g][e] = dpp_add<0xB1>(a[g][e]);
        a[g][e] = dpp_add<0x4E>(a[g][e]);
      }
    }
    if (q < 2) {
      float gi = fsig(a[0][q] + bias[0]);
      float gf = fsig(a[1][q] + bias[1]);
      float gg = ftanh(a[2][q] + bias[2]);
      float go = fsig(a[3][q] + bias[3]);
      c = gf * c + gi * gg;
      hs[nx][rA >> 5][(rA & 31) * 2 + q] = go * ftanh(c);
    }
    __syncthreads();

    // dense epilogue on the just-written h (buffer nx): out[b, S-1-step, :]
    const float4* he = (const float4*)&hs[nx][sl >> 1][0];
    float d0 = 0.0f, d1 = 0.0f;
#pragma unroll
    for (int k = 0; k < 8; ++k) {  // latents 16*sl + 2k, +2k+1
      float4 v = he[(sl & 1) * 8 + k];
      d0 += dw[2 * k] * v.x + dw[2 * k + 1] * v.z;
      d1 += dw[2 * k] * v.y + dw[2 * k + 1] * v.w;
    }
    d0 = dpp_add<0xB1>(d0); d0 = dpp_add<0x4E>(d0); d0 = swz4_add(d0);
    d1 = dpp_add<0xB1>(d1); d1 = dpp_add<0x4E>(d1); d1 = swz4_add(d1);
    if (sl == 0) {
      opA[0] = d0 + dbias;
      opB[0] = d1 + dbias;
    }
    opA -= Fn;
    opB -= Fn;
  }
}

extern "C" void kernel_launch(void* const* d_in, const int* in_sizes, int n_in,
                              void* d_out, int out_size, void* d_ws, size_t ws_size,
                              hipStream_t stream) {
  const float* x     = (const float*)d_in[0];
  const float* Wih_e = (const float*)d_in[1];
  const float* Whh_e = (const float*)d_in[2];
  const float* bih_e = (const float*)d_in[3];
  const float* bhh_e = (const float*)d_in[4];
  const float* Wih_d = (const float*)d_in[5];
  const float* Whh_d = (const float*)d_in[6];
  const float* bih_d = (const float*)d_in[7];
  const float* bhh_d = (const float*)d_in[8];
  const float* Wd    = (const float*)d_in[9];
  const float* bd    = (const float*)d_in[10];
  float* out = (float*)d_out;

  float* Wc = (float*)d_ws;          // 512*128 floats
  float* bc = Wc + (size_t)Gn * Ln;  // 512 floats

  combine_dec_kernel<<<Gn, Ln, 0, stream>>>(Wih_d, Whh_d, bih_d, bhh_d, Wd, bd, Wc, bc);
  rae_persistent_kernel<<<Bn / 2, 512, 0, stream>>>(x, Wih_e, Whh_e, bih_e, bhh_e,
                                                    Wc, bc, Wd, bd, out);
}